// Round 9
// baseline (420.769 us; speedup 1.0000x reference)
//
#include <hip/hip_runtime.h>
#include <hip/hip_bf16.h>
#include <math.h>

// Problem constants
#define Bdim 64
#define Cdim 128
#define Ldim 1024
#define BC   (Bdim * Cdim)      // 8192 rows
#define CLn  (Cdim * Ldim)      // 131072 features
#define TOT  (Bdim * CLn)       // 8388608 elements per (B,C,L) tensor

typedef unsigned short ushort_t;
typedef short s16x8 __attribute__((ext_vector_type(8)));   // 8 bf16 (4 VGPRs)
typedef float f32x4 __attribute__((ext_vector_type(4)));

__device__ __forceinline__ float bf2f(ushort_t u) {
    return __uint_as_float(((unsigned)u) << 16);
}
__device__ __forceinline__ ushort_t f2bf(float f) {
    __hip_bfloat16 h = __float2bfloat16(f);
    return *(ushort_t*)&h;
}
// async global->LDS, 16B per lane; lds base wave-uniform, lane i -> base+i*16B
__device__ __forceinline__ void async16(const ushort_t* g, ushort_t* l) {
    __builtin_amdgcn_global_load_lds(
        (const __attribute__((address_space(1))) unsigned int*)g,
        (__attribute__((address_space(3))) unsigned int*)l, 16, 0, 0);
}
// fast GELU (tanh form): z*sigmoid(1.5957691(z + 0.044715 z^3)); |err|<~3e-4
__device__ __forceinline__ float fast_gelu(float z) {
    float z2 = z * z;
    float inner = fmaf(0.044715f * z2, z, z);
    float e = __expf(-1.5957691216057308f * inner);
    return z * __builtin_amdgcn_rcpf(1.f + e);
}

// ---------------------------------------------------------------------------
// Fused PREP kernel (R7, unchanged): weights->bf16, BN stats, W2 colsums,
// EMA coef, rs zero.
// ---------------------------------------------------------------------------
#define PREP_CONV   15872
#define PREP_BN     (PREP_CONV + 512)
#define PREP_W2CS   (PREP_BN + 48)
#define PREP_COEF   (PREP_W2CS + 128)
#define PREP_TOTAL  (PREP_COEF + 128)

__global__ __launch_bounds__(256) void prep_kernel(
    const float* __restrict__ w1_8, const float* __restrict__ w1_4,
    const float* __restrict__ w1_2, const float* __restrict__ w2_8,
    const float* __restrict__ w2_4, const float* __restrict__ w2_2,
    ushort_t* __restrict__ wdst,
    const float* __restrict__ x, const float* __restrict__ bn_g,
    const float* __restrict__ bn_b, float* __restrict__ scale,
    float* __restrict__ shift,
    float* __restrict__ w2cs,
    const float* __restrict__ al1, const float* __restrict__ al2,
    const float* __restrict__ al4, const float* __restrict__ al8,
    float* __restrict__ coef, float* __restrict__ am,
    float* __restrict__ rs)
{
    __shared__ float red[4][64];
    int bid = blockIdx.x;
    int tid = threadIdx.x;

    if (bid < PREP_CONV) {
        int idx = bid * 256 + tid;
        const float* src; int off;
        if      (idx < 131072)  { src = w1_8; off = 0; }
        else if (idx < 393216)  { src = w1_4; off = 131072; }
        else if (idx < 917504)  { src = w1_2; off = 393216; }
        else if (idx < 1966080) { src = w2_8; off = 917504; }
        else if (idx < 3014656) { src = w2_4; off = 1966080; }
        else                    { src = w2_2; off = 3014656; }
        wdst[idx] = f2bf(src[idx - off]);
    } else if (bid < PREP_BN) {
        int f = (bid - PREP_CONV) * 256 + tid;
        float sum = 0.f, sumsq = 0.f;
        for (int b = 0; b < Bdim; ++b) {
            float v = x[(size_t)b * CLn + f];
            sum += v; sumsq += v * v;
        }
        float mu  = sum * (1.f / Bdim);
        float var = fmaxf(sumsq * (1.f / Bdim) - mu * mu, 0.f);
        float sc  = bn_g[f] / sqrtf(var + 1e-5f);
        scale[f] = sc;
        shift[f] = bn_b[f] - mu * sc;
    } else if (bid < PREP_W2CS) {
        int fl = bid - PREP_BN;
        int bx = fl & 15;
        int by = fl >> 4;
        const float* w = (by == 0) ? w2_8 : (by == 1) ? w2_4 : w2_2;
        int h  = bx * 64 + (tid & 63);
        int ls = tid >> 6;
        float s = 0.f;
        for (int l = ls; l < 1024; l += 4) s += w[(size_t)l * 1024 + h];
        red[ls][tid & 63] = s;
        __syncthreads();
        if (ls == 0)
            w2cs[by * 1024 + h] =
                red[0][tid] + red[1][tid] + red[2][tid] + red[3][tid];
    } else if (bid < PREP_COEF) {
        int c = bid - PREP_W2CS;
        const float* als[4] = {al1, al2, al4, al8};
        const int Lss[4]    = {1024, 512, 256, 128};
        const int offs[4]   = {0, 1024, 1536, 1792};
#pragma unroll
        for (int si = 0; si < 4; ++si) {
            double a  = 1.0 / (1.0 + exp(-(double)als[si][c]));
            double m  = 1.0 - a;
            double lm = log(m);
            int Ls = Lss[si];
            for (int t = tid; t < Ls; t += 256) {
                double dt  = (1.0 - exp((double)(t + 1) * lm)) / a;
                double den = exp((double)(Ls - 1 - t) * lm) * dt;
                double ramp = (den >= 1e-12) ? 1.0 : den * 1e12;
                coef[(size_t)c * 1920 + offs[si] + t] = (float)(ramp / dt);
            }
            if (tid == 0) {
                am[c * 8 + si * 2 + 0] = (float)a;
                am[c * 8 + si * 2 + 1] = (float)m;
            }
        }
    } else {
        int idx = (bid - PREP_COEF) * 256 + tid;
        rs[idx] = 0.f;
    }
}

// ---------------------------------------------------------------------------
// EMA scan helpers (unchanged)
// ---------------------------------------------------------------------------
template<int SEG>
__device__ __forceinline__ void ema_pass1(
    const float* __restrict__ src, float a, float m, bool lead,
    float* __restrict__ xs, float& Sp, float& Sm)
{
    int lane = threadIdx.x & 63;
    if constexpr (SEG >= 4) {
#pragma unroll
        for (int i = 0; i < SEG; i += 4) {
            f32x4 u = *(const f32x4*)&src[lane * SEG + i];
            xs[i + 0] = u.x; xs[i + 1] = u.y;
            xs[i + 2] = u.z; xs[i + 3] = u.w;
        }
    } else {
        float2 u = *(const float2*)&src[lane * 2];
        xs[0] = u.x; xs[1] = u.y;
    }
    float p = 0.f;
#pragma unroll
    for (int i = 0; i < SEG; ++i) {
        float bi = a * xs[i];
        if (lead && lane == 0 && i == 0) bi = xs[0];
        p = fmaf(m, p, bi);
    }
    float sm = m;
#pragma unroll
    for (int i = 1; i < SEG; ++i) sm *= m;
    Sp = p; Sm = sm;
#pragma unroll
    for (int d = 1; d < 64; d <<= 1) {
        float pm = __shfl_up(Sp, d);
        float mm = __shfl_up(Sm, d);
        if (lane >= d) { Sp = fmaf(Sm, pm, Sp); Sm *= mm; }
    }
}

template<int SEG, bool DIFF>
__device__ __forceinline__ float ema_pass2(
    const float* __restrict__ xs, float a, float m, bool lead, float carry,
    const float* __restrict__ cf, ushort_t* __restrict__ dst)
{
    int lane = threadIdx.x & 63;
    float y = carry, diff = 0.f;
    unsigned pk[(SEG + 1) / 2];
#pragma unroll
    for (int i = 0; i < SEG; ++i) {
        float bi = a * xs[i];
        if (lead && lane == 0 && i == 0) bi = xs[0];
        y = fmaf(m, y, bi);
        float tr = y * cf[lane * SEG + i];
        unsigned h = f2bf(tr);
        if ((i & 1) == 0) pk[i >> 1] = h;
        else              pk[i >> 1] |= h << 16;
        if (DIFF) diff += xs[i] - tr;
    }
    if constexpr (SEG == 8) {
        uint4 v; v.x = pk[0]; v.y = pk[1]; v.z = pk[2]; v.w = pk[3];
        *(uint4*)(dst + lane * 8) = v;
    } else if constexpr (SEG == 4) {
        uint2 v; v.x = pk[0]; v.y = pk[1];
        *(uint2*)(dst + lane * 4) = v;
    } else {
        *(unsigned*)(dst + lane * 2) = pk[0];
    }
    return diff;
}

// ---------------------------------------------------------------------------
// MEGA preprocessing kernel (unchanged): one block per row r = b*C + c.
// ---------------------------------------------------------------------------
__global__ __launch_bounds__(256) void pre_kernel(
    const float* __restrict__ x, const float* __restrict__ scale,
    const float* __restrict__ shift,
    const float* __restrict__ cw8, const float* __restrict__ cw4,
    const float* __restrict__ cw2,
    const float* __restrict__ coef, const float* __restrict__ amtab,
    ushort_t* __restrict__ xn_bf, ushort_t* __restrict__ t1_bf,
    ushort_t* __restrict__ A8, ushort_t* __restrict__ A4,
    ushort_t* __restrict__ A2, float* __restrict__ rs)
{
    __shared__ float sxn[1024];
    __shared__ float sxnp[1056];
    __shared__ float sconv[896];
    __shared__ float sP0;
    __shared__ float sdiff[2];
    int r   = blockIdx.x;
    int c   = r & (Cdim - 1);
    int tid = threadIdx.x;

    {
        const float* xr = x + (size_t)r * 1024;
        float4 xv = *(const float4*)(xr + tid * 4);
        float4 sc = *(const float4*)(scale + (size_t)c * 1024 + tid * 4);
        float4 sh = *(const float4*)(shift + (size_t)c * 1024 + tid * 4);
        float v0 = fmaf(xv.x, sc.x, sh.x);
        float v1 = fmaf(xv.y, sc.y, sh.y);
        float v2 = fmaf(xv.z, sc.z, sh.z);
        float v3 = fmaf(xv.w, sc.w, sh.w);
        int p = tid * 4;
        sxn[p + 0] = v0; sxn[p + 1] = v1; sxn[p + 2] = v2; sxn[p + 3] = v3;
        int pp = p + (p >> 5);
        sxnp[pp + 0] = v0; sxnp[pp + 1] = v1;
        sxnp[pp + 2] = v2; sxnp[pp + 3] = v3;
        uint2 pk;
        pk.x = (unsigned)f2bf(v0) | ((unsigned)f2bf(v1) << 16);
        pk.y = (unsigned)f2bf(v2) | ((unsigned)f2bf(v3) << 16);
        *(uint2*)(xn_bf + (size_t)r * 1024 + tid * 4) = pk;
    }
    __syncthreads();

    {
        const float* w2 = cw2 + c * 4;
        unsigned a2pk = 0;
#pragma unroll
        for (int j = 0; j < 2; ++j) {
            int o = tid * 2 + j;
            int start = o * 2 - 1;
            float acc = 0.f;
#pragma unroll
            for (int k = 0; k < 4; ++k) {
                int pos = start + k;
                float v = (pos >= 0 && pos < 1024) ? sxnp[pos + (pos >> 5)] : 0.f;
                acc = fmaf(v, w2[k], acc);
            }
            sconv[o] = acc;
            a2pk |= ((unsigned)f2bf(acc)) << (j * 16);
        }
        *(unsigned*)(A2 + (size_t)r * 512 + tid * 2) = a2pk;
        {
            const float* w4 = cw4 + c * 8;
            int o = tid;
            int start = o * 4 - 2;
            float acc = 0.f;
#pragma unroll
            for (int k = 0; k < 8; ++k) {
                int pos = start + k;
                float v = (pos >= 0 && pos < 1024) ? sxnp[pos + (pos >> 5)] : 0.f;
                acc = fmaf(v, w4[k], acc);
            }
            sconv[512 + o] = acc;
            A4[(size_t)r * 256 + o] = f2bf(acc);
        }
        if (tid < 128) {
            const float* w8 = cw8 + c * 16;
            int o = tid;
            int start = o * 8 - 4;
            float acc = 0.f;
#pragma unroll
            for (int k = 0; k < 16; ++k) {
                int pos = start + k;
                float v = (pos >= 0 && pos < 1024) ? sxnp[pos + (pos >> 5)] : 0.f;
                acc = fmaf(v, w8[k], acc);
            }
            sconv[768 + o] = acc;
            A8[(size_t)r * 128 + o] = f2bf(acc);
        }
    }
    __syncthreads();

    int wave = tid >> 6;
    int lane = tid & 63;
    const float* cf = coef + (size_t)c * 1920;
    const float* am = amtab + c * 8;
    float xs[8];
    float Sp = 0.f, Sm = 1.f, aE = 0.f, mE = 0.f;

    if (wave == 0) {
        aE = am[0]; mE = am[1];
        ema_pass1<8>(sxn, aE, mE, true, xs, Sp, Sm);
        if (lane == 63) sP0 = Sp;
    } else if (wave == 1) {
        aE = am[0]; mE = am[1];
        ema_pass1<8>(sxn + 512, aE, mE, false, xs, Sp, Sm);
    } else if (wave == 2) {
        aE = am[2]; mE = am[3];
        ema_pass1<8>(sconv, aE, mE, true, xs, Sp, Sm);
    } else {
        aE = am[4]; mE = am[5];
        ema_pass1<4>(sconv + 512, aE, mE, true, xs, Sp, Sm);
    }
    __syncthreads();

    float cs  = __shfl_up(Sp, 1);
    float msf = __shfl_up(Sm, 1);
    float carry = lane ? cs : 0.f;

    if (wave == 0) {
        float d = ema_pass2<8, true>(xs, aE, mE, true, carry,
                                     cf, t1_bf + (size_t)r * 1024);
#pragma unroll
        for (int dd = 32; dd; dd >>= 1) d += __shfl_down(d, dd);
        if (lane == 0) sdiff[0] = d;
    } else if (wave == 1) {
        carry += sP0 * (lane ? msf : 1.f);
        float d = ema_pass2<8, true>(xs, aE, mE, false, carry,
                                     cf + 512, t1_bf + (size_t)r * 1024 + 512);
#pragma unroll
        for (int dd = 32; dd; dd >>= 1) d += __shfl_down(d, dd);
        if (lane == 0) sdiff[1] = d;
    } else if (wave == 2) {
        ema_pass2<8, false>(xs, aE, mE, true, carry,
                            cf + 1024, A2 + ((size_t)BC + r) * 512);
    } else {
        ema_pass2<4, false>(xs, aE, mE, true, carry,
                            cf + 1536, A4 + ((size_t)BC + r) * 256);
        float xs2[2];
        aE = am[6]; mE = am[7];
        ema_pass1<2>(sconv + 768, aE, mE, true, xs2, Sp, Sm);
        float cs2 = __shfl_up(Sp, 1);
        float c2  = lane ? cs2 : 0.f;
        ema_pass2<2, false>(xs2, aE, mE, true, c2,
                            cf + 1792, A8 + ((size_t)BC + r) * 128);
    }
    __syncthreads();
    if (tid == 0) rs[3 * BC + r] = sdiff[0] + sdiff[1];
}

// ---------------------------------------------------------------------------
// GEMM1 merged (R7, unchanged — isolate the gemm2 experiment).
// ---------------------------------------------------------------------------
__global__ __launch_bounds__(256, 2) void gemm1_kernel(
    const ushort_t* __restrict__ Abase,
    const ushort_t* __restrict__ Wbase,
    const float* __restrict__ b1_8, const float* __restrict__ b1_4,
    const float* __restrict__ b1_2, const float* __restrict__ w2cs,
    ushort_t* __restrict__ Hbase, float* __restrict__ rs)
{
    int gx = blockIdx.x;
    int z  = 2 - (gx >> 6);
    int mi = gx & 63;
    int K = 128 << z;
    const ushort_t* A  = Abase + (size_t)2 * BC * 128 * ((1 << z) - 1);
    const ushort_t* Bw = Wbase + (size_t)131072 * ((1 << z) - 1);
    const float* bias  = (z == 0) ? b1_8 : (z == 1) ? b1_4 : b1_2;
    ushort_t* Hout     = Hbase + (size_t)z * 2 * TOT;

    __shared__ ushort_t Asu[128 * 64];
    __shared__ ushort_t Ast[128 * 64];
    __shared__ ushort_t Bs[128 * 64];
    int tid  = threadIdx.x;
    int wave = tid >> 6;
    int lane = tid & 63;
    int m0 = mi * 128, n0 = blockIdx.y * 128;
    int wm = (wave & 1) * 64, wn = (wave >> 1) * 64;
    int lrow = lane >> 3;
    int pc   = lane & 7;
    int fr   = lane & 15;
    int quad = lane >> 4;

    f32x4 accu[4][4], acct[4][4];
#pragma unroll
    for (int i = 0; i < 4; ++i)
#pragma unroll
        for (int j = 0; j < 4; ++j) {
            accu[i][j] = (f32x4){0.f, 0.f, 0.f, 0.f};
            acct[i][j] = (f32x4){0.f, 0.f, 0.f, 0.f};
        }

    for (int k0 = 0; k0 < K; k0 += 64) {
        __syncthreads();
#pragma unroll
        for (int i = 0; i < 4; ++i) {
            int rb  = wave * 32 + i * 8;
            int row = rb + lrow;
            int lc  = (pc - row) & 7;
            async16(A + (size_t)(m0 + row) * K + k0 + lc * 8,      &Asu[rb * 64]);
            async16(A + (size_t)(BC + m0 + row) * K + k0 + lc * 8, &Ast[rb * 64]);
            async16(Bw + (size_t)(n0 + row) * K + k0 + lc * 8,     &Bs[rb * 64]);
        }
        __syncthreads();
#pragma unroll
        for (int kk = 0; kk < 64; kk += 32) {
            s16x8 af[4], bfr[4];
            int lcA = (kk >> 3) + quad;
#pragma unroll
            for (int t = 0; t < 4; ++t) {
                int nr  = wn + t * 16 + fr;
                bfr[t] = *(const s16x8*)&Bs[nr * 64 + ((lcA + nr) & 7) * 8];
            }
#pragma unroll
            for (int t = 0; t < 4; ++t) {
                int mr  = wm + t * 16 + fr;
                af[t]  = *(const s16x8*)&Asu[mr * 64 + ((lcA + mr) & 7) * 8];
            }
#pragma unroll
            for (int mt = 0; mt < 4; ++mt)
#pragma unroll
                for (int nt = 0; nt < 4; ++nt)
                    accu[mt][nt] = __builtin_amdgcn_mfma_f32_16x16x32_bf16(
                        af[mt], bfr[nt], accu[mt][nt], 0, 0, 0);
#pragma unroll
            for (int t = 0; t < 4; ++t) {
                int mr  = wm + t * 16 + fr;
                af[t]  = *(const s16x8*)&Ast[mr * 64 + ((lcA + mr) & 7) * 8];
            }
#pragma unroll
            for (int mt = 0; mt < 4; ++mt)
#pragma unroll
                for (int nt = 0; nt < 4; ++nt)
                    acct[mt][nt] = __builtin_amdgcn_mfma_f32_16x16x32_bf16(
                        af[mt], bfr[nt], acct[mt][nt], 0, 0, 0);
        }
    }
    float racc[16];
#pragma unroll
    for (int e = 0; e < 16; ++e) racc[e] = 0.f;
#pragma unroll
    for (int mt = 0; mt < 4; ++mt)
#pragma unroll
        for (int nt = 0; nt < 4; ++nt) {
            int col = n0 + wn + nt * 16 + fr;
            float bcol = bias[col];
            float wcs = w2cs[z * 1024 + col];
#pragma unroll
            for (int rr = 0; rr < 4; ++rr) {
                size_t row = m0 + wm + mt * 16 + quad * 4 + rr;
                float gu = fast_gelu(accu[mt][nt][rr] + bcol);
                float gt = fast_gelu(acct[mt][nt][rr] + bcol);
                Hout[row * 1024 + col]        = f2bf(gu);
                Hout[(BC + row) * 1024 + col] = f2bf(gt);
                racc[mt * 4 + rr] = fmaf(gu - gt, wcs, racc[mt * 4 + rr]);
            }
        }
#pragma unroll
    for (int e = 0; e < 16; ++e) {
        float v = racc[e];
        v += __shfl_xor(v, 1); v += __shfl_xor(v, 2);
        v += __shfl_xor(v, 4); v += __shfl_xor(v, 8);
        if (fr == 0) {
            int mt = e >> 2, rr = e & 3;
            int row = m0 + wm + mt * 16 + quad * 4 + rr;
            atomicAdd(&rs[z * BC + row], v);
        }
    }
}

// ---------------------------------------------------------------------------
// GEMM2 — 256² 8-phase port (T3+T4), virtual-M dual output.
// A-tile (256 rows) = [H-up 128 | H-trend 128] of one m-panel; B = W2 256-col
// panel. 512 threads / 8 waves (wave_m = wave>>2 selects up/trend half,
// wave_n = wave&3 selects 64-col panel). K = 3072 = 48 tiles of 64.
// LDS ring: 2 tile-buffers x 4 regions {A-k0, A-k1, B-k0, B-k1} x 16 KB.
// Per K-tile: 4 phases (ksub, mgroup); each phase: ds_reads + stage 1 region
// + 16 MFMA; ONE barrier per phase; counted vmcnt(8) at phases 1 and 3 only
// (4 half-tiles in flight, never drains). Stage placement derived so every
// region's last reader phase precedes its overwrite phase across a barrier:
//   P1 stages A-k1(t+1), P2: B-k1(t+1)   [other buffer, free since t-1]
//   P3 stages A-k0(t+2), P4: B-k0(t+2)   [this buffer, freed after P2/P1]
// Last tile peels vmcnt to (4, 0). Swizzle = R4's measured-0-conflict scheme.
// Accumulation K-order identical to the 2-phase kernel -> bit-identical.
// Grid (64, 4) x=m-fast: the 4 n-panel sharers of an H panel are ids == mod 8
// -> same XCD L2.
// ---------------------------------------------------------------------------
__global__ __launch_bounds__(512, 2) void gemm2_kernel(
    const ushort_t* __restrict__ Hbase,   // H8 | H4 | H2, each [up|trend] 2*TOT
    const ushort_t* __restrict__ W2base,  // w2b8 | w2b4 | w2b2 contiguous
    const float* __restrict__ b2_8, const float* __restrict__ b2_4,
    const float* __restrict__ b2_2, const float* __restrict__ g,
    const ushort_t* __restrict__ t1_bf, const ushort_t* __restrict__ xn_bf,
    float* __restrict__ trend_out, float* __restrict__ season_out)
{
    __shared__ ushort_t smem[65536];      // 128 KB ring (epilogue: f32 exch)
    int tid  = threadIdx.x;
    int wave = tid >> 6;
    int lane = tid & 63;
    int m0 = blockIdx.x * 128;            // physical rows of this m-panel
    int n0 = blockIdx.y * 256;            // 256-col B panel
    int wm   = wave >> 2;                 // 0 = up half, 1 = trend half
    int wn   = wave & 3;                  // 64-col sub-panel
    int wm128 = wm * 128;
    int rlow = lane >> 2;                 // stage: row within 16-row chunk
    int s4   = lane & 3;                  // stage: linear 16B slot
    int fr   = lane & 15;
    int quad = lane >> 4;
    int bidx = blockIdx.x;                // batch (128 rows = one batch)
    float gv0 = g[bidx * 4 + 0], gv1 = g[bidx * 4 + 1];
    float gv2 = g[bidx * 4 + 2], g1 = g[bidx * 4 + 3];
    float gsv[3] = {gv0, gv1, gv2};

    f32x4 acc[8][4];
#pragma unroll
    for (int i = 0; i < 8; ++i)
#pragma unroll
        for (int j = 0; j < 4; ++j) acc[i][j] = (f32x4){0.f, 0.f, 0.f, 0.f};

    // stage one 16 KB region (256 rows x 32 kcols) of K-tile t; each wave
    // stages rows 32w..32w+31 (2 async16). t>=48 -> skip (epilogue tiles).
    auto stageA = [&](int t, int ksub) {
        if (t >= 48) return;
        int s = t >> 4;
        int k0e = (t & 15) * 64 + ksub * 32;
        ushort_t* dstb = smem + (t & 1) * 32768 + ksub * 8192;
#pragma unroll
        for (int i = 0; i < 2; ++i) {
            int vr = wave * 32 + i * 16 + rlow;
            int cg = (s4 - (vr >> 1)) & 3;
            const ushort_t* src = Hbase + (size_t)s * 2 * TOT
                + (size_t)(vr >> 7) * TOT
                + (size_t)(m0 + (vr & 127)) * 1024 + k0e + cg * 8;
            async16(src, dstb + (wave * 32 + i * 16) * 32);
        }
    };
    auto stageB = [&](int t, int ksub) {
        if (t >= 48) return;
        int s = t >> 4;
        int k0e = (t & 15) * 64 + ksub * 32;
        ushort_t* dstb = smem + (t & 1) * 32768 + 16384 + ksub * 8192;
#pragma unroll
        for (int i = 0; i < 2; ++i) {
            int vr = wave * 32 + i * 16 + rlow;
            int cg = (s4 - (vr >> 1)) & 3;
            const ushort_t* src = W2base + (size_t)s * 1048576
                + (size_t)(n0 + vr) * 1024 + k0e + cg * 8;
            async16(src, dstb + (wave * 32 + i * 16) * 32);
        }
    };

    // prologue: mimic the steady-state stage-stream ages (6 half-tiles)
    stageA(0, 0); stageB(0, 0);
    stageA(0, 1); stageB(0, 1);
    stageA(1, 0); stageB(1, 0);

    s16x8 af[4], bf[4];
    for (int kt = 0; kt < 48; ++kt) {
        if (kt == 16 || kt == 32) {        // gate fold at scale boundary
            int s = kt >> 4;
            float rr_ = gsv[s - 1] / fmaxf(gsv[s], 1e-30f);
#pragma unroll
            for (int i = 0; i < 8; ++i)
#pragma unroll
                for (int j = 0; j < 4; ++j)
#pragma unroll
                    for (int e = 0; e < 4; ++e) acc[i][j][e] *= rr_;
        }
        const ushort_t* Ab = smem + (kt & 1) * 32768;
        const ushort_t* Bb = Ab + 16384;

        // ---- P1: ksub=0, A frags 0-3 + B frags (k0) ----
        if (kt < 47) { asm volatile("s_waitcnt vmcnt(8)" ::: "memory"); }
        else         { asm volatile("s_waitcnt vmcnt(4)" ::: "memory"); }
        __builtin_amdgcn_s_barrier();
        __builtin_amdgcn_sched_barrier(0);
#pragma unroll
        for (int q = 0; q < 4; ++q) {
            int vrA = wm128 + q * 16 + fr;
            af[q] = *(const s16x8*)&Ab[vrA * 32 + ((quad + (vrA >> 1)) & 3) * 8];
            int vrB = wn * 64 + q * 16 + fr;
            bf[q] = *(const s16x8*)&Bb[vrB * 32 + ((quad + (vrB >> 1)) & 3) * 8];
        }
        stageA(kt + 1, 1);
        __builtin_amdgcn_s_setprio(1);
#pragma unroll
        for (int mt = 0; mt < 4; ++mt)
#pragma unroll
            for (int nt = 0; nt < 4; ++nt)
                acc[mt][nt] = __builtin_amdgcn_mfma_f32_16x16x32_bf16(
                    af[mt], bf[nt], acc[mt][nt], 0, 0, 0);
        __builtin_amdgcn_s_setprio(0);
        __builtin_amdgcn_sched_barrier(0);

        // ---- P2: ksub=0, A frags 4-7 (reuse B) ----
        __builtin_amdgcn_s_barrier();
        __builtin_amdgcn_sched_barrier(0);
#pragma unroll
        for (int q = 0; q < 4; ++q) {
            int vrA = wm128 + (4 + q) * 16 + fr;
            af[q] = *(const s16x8*)&Ab[vrA * 32 + ((quad + (vrA >> 1)) & 3) * 8];
        }
        stageB(kt + 1, 1);
        __builtin_amdgcn_s_setprio(1);
#pragma unroll
        for (int mt = 0; mt < 4; ++mt)
#pragma unroll
            for (int nt = 0; nt < 4; ++nt)
                acc[4 + mt][nt] = __builtin_amdgcn_mfma_f32_16x16x32_bf16(
                    af[mt], bf[nt], acc[4 + mt][nt], 0, 0, 0);
        __builtin_amdgcn_s_setprio(0);
        __builtin_amdgcn_sched_barrier(0);

        // ---- P3: ksub=1, A frags 0-3 + B frags (k1) ----
        if (kt < 47) { asm volatile("s_waitcnt vmcnt(8)" ::: "memory"); }
        else         { asm volatile("s_waitcnt vmcnt(0)" ::: "memory"); }
        __builtin_amdgcn_s_barrier();
        __builtin_amdgcn_sched_barrier(0);
#pragma unroll
        for (int q = 0; q < 4; ++q) {
            int vrA = wm128 + q * 16 + fr;
            af[q] = *(const s16x8*)&Ab[8192 + vrA * 32 + ((quad + (vrA >> 1)) & 3) * 8];
            int vrB = wn * 64 + q * 16 + fr;
            bf[q] = *(const s16x8*)&Bb[8192 + vrB * 32 + ((quad + (vrB >> 1)) & 3) * 8];
        }
        stageA(kt + 2, 0);
        __builtin_amdgcn_s_setprio(1);
#pragma unroll
        for (int mt = 0; mt < 4; ++mt)
#pragma unroll
            for (int nt = 0; nt < 4; ++nt)
                acc[mt][nt] = __builtin_amdgcn_mfma_f32_16x16x32_bf16(
                    af[mt], bf[nt], acc[mt][nt], 0, 0, 0);
        __builtin_amdgcn_s_setprio(0);
        __builtin_amdgcn_sched_barrier(0);

        // ---- P4: ksub=1, A frags 4-7 (reuse B) ----
        __builtin_amdgcn_s_barrier();
        __builtin_amdgcn_sched_barrier(0);
#pragma unroll
        for (int q = 0; q < 4; ++q) {
            int vrA = wm128 + (4 + q) * 16 + fr;
            af[q] = *(const s16x8*)&Ab[8192 + vrA * 32 + ((quad + (vrA >> 1)) & 3) * 8];
        }
        stageB(kt + 2, 0);
        __builtin_amdgcn_s_setprio(1);
#pragma unroll
        for (int mt = 0; mt < 4; ++mt)
#pragma unroll
            for (int nt = 0; nt < 4; ++nt)
                acc[4 + mt][nt] = __builtin_amdgcn_mfma_f32_16x16x32_bf16(
                    af[mt], bf[nt], acc[4 + mt][nt], 0, 0, 0);
        __builtin_amdgcn_s_setprio(0);
        __builtin_amdgcn_sched_barrier(0);
    }

    // epilogue — D layout per frag: m = quad*4 + rr, n = fr.
    // T-waves (wm=1) write trend and stash tr in LDS; U-waves read and write
    // season (fp-identical to the in-register path).
    __syncthreads();
    float* exch = (float*)smem;            // [4 panels][128][64] f32 = 128 KB
    if (wm == 1) {
#pragma unroll
        for (int f = 0; f < 8; ++f)
#pragma unroll
            for (int j = 0; j < 4; ++j) {
                int col = n0 + wn * 64 + j * 16 + fr;
                float cb2 = gv0 * b2_8[col] + gv1 * b2_4[col] + gv2 * b2_2[col];
#pragma unroll
                for (int rr = 0; rr < 4; ++rr) {
                    int lrow = f * 16 + quad * 4 + rr;
                    size_t idx = (size_t)(m0 + lrow) * 1024 + col;
                    float tr = acc[f][j][rr] * gv2 + cb2 + g1 * bf2f(t1_bf[idx]);
                    trend_out[idx] = tr;
                    exch[wn * 8192 + lrow * 64 + j * 16 + fr] = tr;
                }
            }
    }
    __syncthreads();
    if (wm == 0) {
#pragma unroll
        for (int f = 0; f < 8; ++f)
#pragma unroll
            for (int j = 0; j < 4; ++j) {
                int col = n0 + wn * 64 + j * 16 + fr;
                float cb2 = gv0 * b2_8[col] + gv1 * b2_4[col] + gv2 * b2_2[col];
#pragma unroll
                for (int rr = 0; rr < 4; ++rr) {
                    int lrow = f * 16 + quad * 4 + rr;
                    size_t idx = (size_t)(m0 + lrow) * 1024 + col;
                    float tr = exch[wn * 8192 + lrow * 64 + j * 16 + fr];
                    float se = acc[f][j][rr] * gv2 + cb2
                             + g1 * bf2f(xn_bf[idx]) - tr;
                    season_out[idx] = se;
                }
            }
    }
}

// ---------------------------------------------------------------------------
// gates: sigmoid(mean_L(season) . gw + gb) per scale, then normalize over 4
// ---------------------------------------------------------------------------
__global__ __launch_bounds__(128) void gate_kernel(
    const float* __restrict__ rs,
    const float* __restrict__ gw8, const float* __restrict__ gb8,
    const float* __restrict__ gw4, const float* __restrict__ gb4,
    const float* __restrict__ gw2, const float* __restrict__ gb2,
    const float* __restrict__ gw1, const float* __restrict__ gb1,
    float* __restrict__ g)
{
    int b = blockIdx.x;
    int c = threadIdx.x;
    const float* gws[4] = {gw8, gw4, gw2, gw1};
    const float* gbs[4] = {gb8, gb4, gb2, gb1};
    __shared__ float buf[128];
    __shared__ float gates[4];
    for (int si = 0; si < 4; ++si) {
        buf[c] = rs[si * BC + b * Cdim + c] * (1.f / Ldim) * gws[si][c];
        __syncthreads();
        for (int off = 64; off >= 1; off >>= 1) {
            if (c < off) buf[c] += buf[c + off];
            __syncthreads();
        }
        if (c == 0) {
            float z = buf[0] + gbs[si][0];
            gates[si] = 1.f / (1.f + expf(-z));
        }
        __syncthreads();
    }
    if (c == 0) {
        float s = gates[0] + gates[1] + gates[2] + gates[3] + 1e-6f;
#pragma unroll
        for (int si = 0; si < 4; ++si) g[b * 4 + si] = gates[si] / s;
    }
}

// ---------------------------------------------------------------------------
extern "C" void kernel_launch(void* const* d_in, const int* in_sizes, int n_in,
                              void* d_out, int out_size, void* d_ws, size_t ws_size,
                              hipStream_t stream)
{
    const float* x    = (const float*)d_in[0];
    const float* bn_g = (const float*)d_in[1];
    const float* bn_b = (const float*)d_in[2];
    const float* cw8  = (const float*)d_in[3];
    const float* w1_8 = (const float*)d_in[4];
    const float* b1_8 = (const float*)d_in[5];
    const float* w2_8 = (const float*)d_in[6];
    const float* b2_8 = (const float*)d_in[7];
    const float* cw4  = (const float*)d_in[8];
    const float* w1_4 = (const float*)d_in[9];
    const float* b1_4 = (const float*)d_in[10];
    const float* w2_4 = (const float*)d_in[11];
    const float* b2_4 = (const float*)d_in[12];
    const float* cw2  = (const float*)d_in[13];
    const float* w1_2 = (const float*)d_in[14];
    const float* b1_2 = (const float*)d_in[15];
    const float* w2_2 = (const float*)d_in[16];
    const float* b2_2 = (const float*)d_in[17];
    const float* gw8  = (const float*)d_in[18];
    const float* gb8  = (const float*)d_in[19];
    const float* al8  = (const float*)d_in[20];
    const float* gw4  = (const float*)d_in[21];
    const float* gb4  = (const float*)d_in[22];
    const float* al4  = (const float*)d_in[23];
    const float* gw2  = (const float*)d_in[24];
    const float* gb2  = (const float*)d_in[25];
    const float* al2  = (const float*)d_in[26];
    const float* gw1  = (const float*)d_in[27];
    const float* gb1  = (const float*)d_in[28];
    const float* al1  = (const float*)d_in[29];

    // workspace (~140 MB)
    ushort_t* p_xn  = (ushort_t*)d_ws;                 // TOT bf16
    ushort_t* p_t1  = p_xn + TOT;                      // TOT bf16
    ushort_t* p_H   = p_t1 + TOT;                      // 6*TOT bf16 (H8|H4|H2)
    ushort_t* p_wb  = p_H + 6 * (size_t)TOT;           // 4063232 bf16 weights
    ushort_t* p_w1b = p_wb;                            // w1b8|w1b4|w1b2
    ushort_t* p_w2b = p_wb + 917504;                   // w2b8|w2b4|w2b2
    float*    p_sc  = (float*)(p_wb + 4063232);        // CLn
    float*    p_sh  = p_sc + CLn;                      // CLn
    float*    p_w2cs = p_sh + CLn;                     // 3*1024
    float*    p_rs  = p_w2cs + 3 * 1024;               // 4*BC
    float*    p_g   = p_rs + 4 * BC;                   // 256
    float*    p_coef = (float*)p_H;                    // 128*1920 floats (aliased)
    float*    p_am   = p_coef + 128 * 1920;            // 128*8 floats
    ushort_t* p_A8 = (ushort_t*)d_out;                 // 2*BC*128
    ushort_t* p_A4 = p_A8 + 2 * (size_t)BC * 128;      // 2*BC*256
    ushort_t* p_A2 = p_A4 + 2 * (size_t)BC * 256;      // 2*BC*512
    float*    p_season = (float*)d_out;
    float*    p_trend  = (float*)d_out + TOT;

    prep_kernel<<<PREP_TOTAL, 256, 0, stream>>>(
        w1_8, w1_4, w1_2, w2_8, w2_4, w2_2, p_wb,
        x, bn_g, bn_b, p_sc, p_sh,
        p_w2cs,
        al1, al2, al4, al8, p_coef, p_am,
        p_rs);

    pre_kernel<<<BC, 256, 0, stream>>>(x, p_sc, p_sh, cw8, cw4, cw2,
                                       p_coef, p_am,
                                       p_xn, p_t1, p_A8, p_A4, p_A2, p_rs);

    gemm1_kernel<<<dim3(192, 8), 256, 0, stream>>>(
        p_A8, p_w1b, b1_8, b1_4, b1_2, p_w2cs, p_H, p_rs);

    gate_kernel<<<Bdim, 128, 0, stream>>>(p_rs, gw8, gb8, gw4, gb4,
                                          gw2, gb2, gw1, gb1, p_g);

    // GEMM2: 256-sq 8-phase schedule, virtual-M dual output
    gemm2_kernel<<<dim3(64, 4), 512, 0, stream>>>(
        p_H, p_w2b, b2_8, b2_4, b2_2, p_g, p_t1, p_xn, p_trend, p_season);
}

// Round 10
// 410.941 us; speedup vs baseline: 1.0239x; 1.0239x over previous
//
#include <hip/hip_runtime.h>
#include <hip/hip_bf16.h>
#include <math.h>

// Problem constants
#define Bdim 64
#define Cdim 128
#define Ldim 1024
#define BC   (Bdim * Cdim)      // 8192 rows
#define CLn  (Cdim * Ldim)      // 131072 features
#define TOT  (Bdim * CLn)       // 8388608 elements per (B,C,L) tensor

typedef unsigned short ushort_t;
typedef short s16x8 __attribute__((ext_vector_type(8)));   // 8 bf16 (4 VGPRs)
typedef float f32x4 __attribute__((ext_vector_type(4)));

__device__ __forceinline__ float bf2f(ushort_t u) {
    return __uint_as_float(((unsigned)u) << 16);
}
__device__ __forceinline__ ushort_t f2bf(float f) {
    __hip_bfloat16 h = __float2bfloat16(f);
    return *(ushort_t*)&h;
}
// async global->LDS, 16B per lane; lds base wave-uniform, lane i -> base+i*16B
__device__ __forceinline__ void async16(const ushort_t* g, ushort_t* l) {
    __builtin_amdgcn_global_load_lds(
        (const __attribute__((address_space(1))) unsigned int*)g,
        (__attribute__((address_space(3))) unsigned int*)l, 16, 0, 0);
}
// fast GELU (tanh form): z*sigmoid(1.5957691(z + 0.044715 z^3)); |err|<~3e-4
__device__ __forceinline__ float fast_gelu(float z) {
    float z2 = z * z;
    float inner = fmaf(0.044715f * z2, z, z);
    float e = __expf(-1.5957691216057308f * inner);
    return z * __builtin_amdgcn_rcpf(1.f + e);
}

// ---------------------------------------------------------------------------
// Fused PREP kernel (R7, unchanged): weights->bf16, BN stats, W2 colsums,
// EMA coef, rs zero.
// ---------------------------------------------------------------------------
#define PREP_CONV   15872
#define PREP_BN     (PREP_CONV + 512)
#define PREP_W2CS   (PREP_BN + 48)
#define PREP_COEF   (PREP_W2CS + 128)
#define PREP_TOTAL  (PREP_COEF + 128)

__global__ __launch_bounds__(256) void prep_kernel(
    const float* __restrict__ w1_8, const float* __restrict__ w1_4,
    const float* __restrict__ w1_2, const float* __restrict__ w2_8,
    const float* __restrict__ w2_4, const float* __restrict__ w2_2,
    ushort_t* __restrict__ wdst,
    const float* __restrict__ x, const float* __restrict__ bn_g,
    const float* __restrict__ bn_b, float* __restrict__ scale,
    float* __restrict__ shift,
    float* __restrict__ w2cs,
    const float* __restrict__ al1, const float* __restrict__ al2,
    const float* __restrict__ al4, const float* __restrict__ al8,
    float* __restrict__ coef, float* __restrict__ am,
    float* __restrict__ rs)
{
    __shared__ float red[4][64];
    int bid = blockIdx.x;
    int tid = threadIdx.x;

    if (bid < PREP_CONV) {
        int idx = bid * 256 + tid;
        const float* src; int off;
        if      (idx < 131072)  { src = w1_8; off = 0; }
        else if (idx < 393216)  { src = w1_4; off = 131072; }
        else if (idx < 917504)  { src = w1_2; off = 393216; }
        else if (idx < 1966080) { src = w2_8; off = 917504; }
        else if (idx < 3014656) { src = w2_4; off = 1966080; }
        else                    { src = w2_2; off = 3014656; }
        wdst[idx] = f2bf(src[idx - off]);
    } else if (bid < PREP_BN) {
        int f = (bid - PREP_CONV) * 256 + tid;
        float sum = 0.f, sumsq = 0.f;
        for (int b = 0; b < Bdim; ++b) {
            float v = x[(size_t)b * CLn + f];
            sum += v; sumsq += v * v;
        }
        float mu  = sum * (1.f / Bdim);
        float var = fmaxf(sumsq * (1.f / Bdim) - mu * mu, 0.f);
        float sc  = bn_g[f] / sqrtf(var + 1e-5f);
        scale[f] = sc;
        shift[f] = bn_b[f] - mu * sc;
    } else if (bid < PREP_W2CS) {
        int fl = bid - PREP_BN;
        int bx = fl & 15;
        int by = fl >> 4;
        const float* w = (by == 0) ? w2_8 : (by == 1) ? w2_4 : w2_2;
        int h  = bx * 64 + (tid & 63);
        int ls = tid >> 6;
        float s = 0.f;
        for (int l = ls; l < 1024; l += 4) s += w[(size_t)l * 1024 + h];
        red[ls][tid & 63] = s;
        __syncthreads();
        if (ls == 0)
            w2cs[by * 1024 + h] =
                red[0][tid] + red[1][tid] + red[2][tid] + red[3][tid];
    } else if (bid < PREP_COEF) {
        int c = bid - PREP_W2CS;
        const float* als[4] = {al1, al2, al4, al8};
        const int Lss[4]    = {1024, 512, 256, 128};
        const int offs[4]   = {0, 1024, 1536, 1792};
#pragma unroll
        for (int si = 0; si < 4; ++si) {
            double a  = 1.0 / (1.0 + exp(-(double)als[si][c]));
            double m  = 1.0 - a;
            double lm = log(m);
            int Ls = Lss[si];
            for (int t = tid; t < Ls; t += 256) {
                double dt  = (1.0 - exp((double)(t + 1) * lm)) / a;
                double den = exp((double)(Ls - 1 - t) * lm) * dt;
                double ramp = (den >= 1e-12) ? 1.0 : den * 1e12;
                coef[(size_t)c * 1920 + offs[si] + t] = (float)(ramp / dt);
            }
            if (tid == 0) {
                am[c * 8 + si * 2 + 0] = (float)a;
                am[c * 8 + si * 2 + 1] = (float)m;
            }
        }
    } else {
        int idx = (bid - PREP_COEF) * 256 + tid;
        rs[idx] = 0.f;
    }
}

// ---------------------------------------------------------------------------
// EMA scan helpers (unchanged)
// ---------------------------------------------------------------------------
template<int SEG>
__device__ __forceinline__ void ema_pass1(
    const float* __restrict__ src, float a, float m, bool lead,
    float* __restrict__ xs, float& Sp, float& Sm)
{
    int lane = threadIdx.x & 63;
    if constexpr (SEG >= 4) {
#pragma unroll
        for (int i = 0; i < SEG; i += 4) {
            f32x4 u = *(const f32x4*)&src[lane * SEG + i];
            xs[i + 0] = u.x; xs[i + 1] = u.y;
            xs[i + 2] = u.z; xs[i + 3] = u.w;
        }
    } else {
        float2 u = *(const float2*)&src[lane * 2];
        xs[0] = u.x; xs[1] = u.y;
    }
    float p = 0.f;
#pragma unroll
    for (int i = 0; i < SEG; ++i) {
        float bi = a * xs[i];
        if (lead && lane == 0 && i == 0) bi = xs[0];
        p = fmaf(m, p, bi);
    }
    float sm = m;
#pragma unroll
    for (int i = 1; i < SEG; ++i) sm *= m;
    Sp = p; Sm = sm;
#pragma unroll
    for (int d = 1; d < 64; d <<= 1) {
        float pm = __shfl_up(Sp, d);
        float mm = __shfl_up(Sm, d);
        if (lane >= d) { Sp = fmaf(Sm, pm, Sp); Sm *= mm; }
    }
}

template<int SEG, bool DIFF>
__device__ __forceinline__ float ema_pass2(
    const float* __restrict__ xs, float a, float m, bool lead, float carry,
    const float* __restrict__ cf, ushort_t* __restrict__ dst)
{
    int lane = threadIdx.x & 63;
    float y = carry, diff = 0.f;
    unsigned pk[(SEG + 1) / 2];
#pragma unroll
    for (int i = 0; i < SEG; ++i) {
        float bi = a * xs[i];
        if (lead && lane == 0 && i == 0) bi = xs[0];
        y = fmaf(m, y, bi);
        float tr = y * cf[lane * SEG + i];
        unsigned h = f2bf(tr);
        if ((i & 1) == 0) pk[i >> 1] = h;
        else              pk[i >> 1] |= h << 16;
        if (DIFF) diff += xs[i] - tr;
    }
    if constexpr (SEG == 8) {
        uint4 v; v.x = pk[0]; v.y = pk[1]; v.z = pk[2]; v.w = pk[3];
        *(uint4*)(dst + lane * 8) = v;
    } else if constexpr (SEG == 4) {
        uint2 v; v.x = pk[0]; v.y = pk[1];
        *(uint2*)(dst + lane * 4) = v;
    } else {
        *(unsigned*)(dst + lane * 2) = pk[0];
    }
    return diff;
}

// ---------------------------------------------------------------------------
// MEGA preprocessing kernel (unchanged): one block per row r = b*C + c.
// ---------------------------------------------------------------------------
__global__ __launch_bounds__(256) void pre_kernel(
    const float* __restrict__ x, const float* __restrict__ scale,
    const float* __restrict__ shift,
    const float* __restrict__ cw8, const float* __restrict__ cw4,
    const float* __restrict__ cw2,
    const float* __restrict__ coef, const float* __restrict__ amtab,
    ushort_t* __restrict__ xn_bf, ushort_t* __restrict__ t1_bf,
    ushort_t* __restrict__ A8, ushort_t* __restrict__ A4,
    ushort_t* __restrict__ A2, float* __restrict__ rs)
{
    __shared__ float sxn[1024];
    __shared__ float sxnp[1056];
    __shared__ float sconv[896];
    __shared__ float sP0;
    __shared__ float sdiff[2];
    int r   = blockIdx.x;
    int c   = r & (Cdim - 1);
    int tid = threadIdx.x;

    {
        const float* xr = x + (size_t)r * 1024;
        float4 xv = *(const float4*)(xr + tid * 4);
        float4 sc = *(const float4*)(scale + (size_t)c * 1024 + tid * 4);
        float4 sh = *(const float4*)(shift + (size_t)c * 1024 + tid * 4);
        float v0 = fmaf(xv.x, sc.x, sh.x);
        float v1 = fmaf(xv.y, sc.y, sh.y);
        float v2 = fmaf(xv.z, sc.z, sh.z);
        float v3 = fmaf(xv.w, sc.w, sh.w);
        int p = tid * 4;
        sxn[p + 0] = v0; sxn[p + 1] = v1; sxn[p + 2] = v2; sxn[p + 3] = v3;
        int pp = p + (p >> 5);
        sxnp[pp + 0] = v0; sxnp[pp + 1] = v1;
        sxnp[pp + 2] = v2; sxnp[pp + 3] = v3;
        uint2 pk;
        pk.x = (unsigned)f2bf(v0) | ((unsigned)f2bf(v1) << 16);
        pk.y = (unsigned)f2bf(v2) | ((unsigned)f2bf(v3) << 16);
        *(uint2*)(xn_bf + (size_t)r * 1024 + tid * 4) = pk;
    }
    __syncthreads();

    {
        const float* w2 = cw2 + c * 4;
        unsigned a2pk = 0;
#pragma unroll
        for (int j = 0; j < 2; ++j) {
            int o = tid * 2 + j;
            int start = o * 2 - 1;
            float acc = 0.f;
#pragma unroll
            for (int k = 0; k < 4; ++k) {
                int pos = start + k;
                float v = (pos >= 0 && pos < 1024) ? sxnp[pos + (pos >> 5)] : 0.f;
                acc = fmaf(v, w2[k], acc);
            }
            sconv[o] = acc;
            a2pk |= ((unsigned)f2bf(acc)) << (j * 16);
        }
        *(unsigned*)(A2 + (size_t)r * 512 + tid * 2) = a2pk;
        {
            const float* w4 = cw4 + c * 8;
            int o = tid;
            int start = o * 4 - 2;
            float acc = 0.f;
#pragma unroll
            for (int k = 0; k < 8; ++k) {
                int pos = start + k;
                float v = (pos >= 0 && pos < 1024) ? sxnp[pos + (pos >> 5)] : 0.f;
                acc = fmaf(v, w4[k], acc);
            }
            sconv[512 + o] = acc;
            A4[(size_t)r * 256 + o] = f2bf(acc);
        }
        if (tid < 128) {
            const float* w8 = cw8 + c * 16;
            int o = tid;
            int start = o * 8 - 4;
            float acc = 0.f;
#pragma unroll
            for (int k = 0; k < 16; ++k) {
                int pos = start + k;
                float v = (pos >= 0 && pos < 1024) ? sxnp[pos + (pos >> 5)] : 0.f;
                acc = fmaf(v, w8[k], acc);
            }
            sconv[768 + o] = acc;
            A8[(size_t)r * 128 + o] = f2bf(acc);
        }
    }
    __syncthreads();

    int wave = tid >> 6;
    int lane = tid & 63;
    const float* cf = coef + (size_t)c * 1920;
    const float* am = amtab + c * 8;
    float xs[8];
    float Sp = 0.f, Sm = 1.f, aE = 0.f, mE = 0.f;

    if (wave == 0) {
        aE = am[0]; mE = am[1];
        ema_pass1<8>(sxn, aE, mE, true, xs, Sp, Sm);
        if (lane == 63) sP0 = Sp;
    } else if (wave == 1) {
        aE = am[0]; mE = am[1];
        ema_pass1<8>(sxn + 512, aE, mE, false, xs, Sp, Sm);
    } else if (wave == 2) {
        aE = am[2]; mE = am[3];
        ema_pass1<8>(sconv, aE, mE, true, xs, Sp, Sm);
    } else {
        aE = am[4]; mE = am[5];
        ema_pass1<4>(sconv + 512, aE, mE, true, xs, Sp, Sm);
    }
    __syncthreads();

    float cs  = __shfl_up(Sp, 1);
    float msf = __shfl_up(Sm, 1);
    float carry = lane ? cs : 0.f;

    if (wave == 0) {
        float d = ema_pass2<8, true>(xs, aE, mE, true, carry,
                                     cf, t1_bf + (size_t)r * 1024);
#pragma unroll
        for (int dd = 32; dd; dd >>= 1) d += __shfl_down(d, dd);
        if (lane == 0) sdiff[0] = d;
    } else if (wave == 1) {
        carry += sP0 * (lane ? msf : 1.f);
        float d = ema_pass2<8, true>(xs, aE, mE, false, carry,
                                     cf + 512, t1_bf + (size_t)r * 1024 + 512);
#pragma unroll
        for (int dd = 32; dd; dd >>= 1) d += __shfl_down(d, dd);
        if (lane == 0) sdiff[1] = d;
    } else if (wave == 2) {
        ema_pass2<8, false>(xs, aE, mE, true, carry,
                            cf + 1024, A2 + ((size_t)BC + r) * 512);
    } else {
        ema_pass2<4, false>(xs, aE, mE, true, carry,
                            cf + 1536, A4 + ((size_t)BC + r) * 256);
        float xs2[2];
        aE = am[6]; mE = am[7];
        ema_pass1<2>(sconv + 768, aE, mE, true, xs2, Sp, Sm);
        float cs2 = __shfl_up(Sp, 1);
        float c2  = lane ? cs2 : 0.f;
        ema_pass2<2, false>(xs2, aE, mE, true, c2,
                            cf + 1792, A8 + ((size_t)BC + r) * 128);
    }
    __syncthreads();
    if (tid == 0) rs[3 * BC + r] = sdiff[0] + sdiff[1];
}

// ---------------------------------------------------------------------------
// GEMM1 merged (R7/R8 measured-best structure, unchanged).
// ---------------------------------------------------------------------------
__global__ __launch_bounds__(256, 2) void gemm1_kernel(
    const ushort_t* __restrict__ Abase,
    const ushort_t* __restrict__ Wbase,
    const float* __restrict__ b1_8, const float* __restrict__ b1_4,
    const float* __restrict__ b1_2, const float* __restrict__ w2cs,
    ushort_t* __restrict__ Hbase, float* __restrict__ rs)
{
    int gx = blockIdx.x;
    int z  = 2 - (gx >> 6);
    int mi = gx & 63;
    int K = 128 << z;
    const ushort_t* A  = Abase + (size_t)2 * BC * 128 * ((1 << z) - 1);
    const ushort_t* Bw = Wbase + (size_t)131072 * ((1 << z) - 1);
    const float* bias  = (z == 0) ? b1_8 : (z == 1) ? b1_4 : b1_2;
    ushort_t* Hout     = Hbase + (size_t)z * 2 * TOT;

    __shared__ ushort_t Asu[128 * 64];
    __shared__ ushort_t Ast[128 * 64];
    __shared__ ushort_t Bs[128 * 64];
    int tid  = threadIdx.x;
    int wave = tid >> 6;
    int lane = tid & 63;
    int m0 = mi * 128, n0 = blockIdx.y * 128;
    int wm = (wave & 1) * 64, wn = (wave >> 1) * 64;
    int lrow = lane >> 3;
    int pc   = lane & 7;
    int fr   = lane & 15;
    int quad = lane >> 4;

    f32x4 accu[4][4], acct[4][4];
#pragma unroll
    for (int i = 0; i < 4; ++i)
#pragma unroll
        for (int j = 0; j < 4; ++j) {
            accu[i][j] = (f32x4){0.f, 0.f, 0.f, 0.f};
            acct[i][j] = (f32x4){0.f, 0.f, 0.f, 0.f};
        }

    for (int k0 = 0; k0 < K; k0 += 64) {
        __syncthreads();
#pragma unroll
        for (int i = 0; i < 4; ++i) {
            int rb  = wave * 32 + i * 8;
            int row = rb + lrow;
            int lc  = (pc - row) & 7;
            async16(A + (size_t)(m0 + row) * K + k0 + lc * 8,      &Asu[rb * 64]);
            async16(A + (size_t)(BC + m0 + row) * K + k0 + lc * 8, &Ast[rb * 64]);
            async16(Bw + (size_t)(n0 + row) * K + k0 + lc * 8,     &Bs[rb * 64]);
        }
        __syncthreads();
#pragma unroll
        for (int kk = 0; kk < 64; kk += 32) {
            s16x8 af[4], bfr[4];
            int lcA = (kk >> 3) + quad;
#pragma unroll
            for (int t = 0; t < 4; ++t) {
                int nr  = wn + t * 16 + fr;
                bfr[t] = *(const s16x8*)&Bs[nr * 64 + ((lcA + nr) & 7) * 8];
            }
#pragma unroll
            for (int t = 0; t < 4; ++t) {
                int mr  = wm + t * 16 + fr;
                af[t]  = *(const s16x8*)&Asu[mr * 64 + ((lcA + mr) & 7) * 8];
            }
#pragma unroll
            for (int mt = 0; mt < 4; ++mt)
#pragma unroll
                for (int nt = 0; nt < 4; ++nt)
                    accu[mt][nt] = __builtin_amdgcn_mfma_f32_16x16x32_bf16(
                        af[mt], bfr[nt], accu[mt][nt], 0, 0, 0);
#pragma unroll
            for (int t = 0; t < 4; ++t) {
                int mr  = wm + t * 16 + fr;
                af[t]  = *(const s16x8*)&Ast[mr * 64 + ((lcA + mr) & 7) * 8];
            }
#pragma unroll
            for (int mt = 0; mt < 4; ++mt)
#pragma unroll
                for (int nt = 0; nt < 4; ++nt)
                    acct[mt][nt] = __builtin_amdgcn_mfma_f32_16x16x32_bf16(
                        af[mt], bfr[nt], acct[mt][nt], 0, 0, 0);
        }
    }
    float racc[16];
#pragma unroll
    for (int e = 0; e < 16; ++e) racc[e] = 0.f;
#pragma unroll
    for (int mt = 0; mt < 4; ++mt)
#pragma unroll
        for (int nt = 0; nt < 4; ++nt) {
            int col = n0 + wn + nt * 16 + fr;
            float bcol = bias[col];
            float wcs = w2cs[z * 1024 + col];
#pragma unroll
            for (int rr = 0; rr < 4; ++rr) {
                size_t row = m0 + wm + mt * 16 + quad * 4 + rr;
                float gu = fast_gelu(accu[mt][nt][rr] + bcol);
                float gt = fast_gelu(acct[mt][nt][rr] + bcol);
                Hout[row * 1024 + col]        = f2bf(gu);
                Hout[(BC + row) * 1024 + col] = f2bf(gt);
                racc[mt * 4 + rr] = fmaf(gu - gt, wcs, racc[mt * 4 + rr]);
            }
        }
#pragma unroll
    for (int e = 0; e < 16; ++e) {
        float v = racc[e];
        v += __shfl_xor(v, 1); v += __shfl_xor(v, 2);
        v += __shfl_xor(v, 4); v += __shfl_xor(v, 8);
        if (fr == 0) {
            int mt = e >> 2, rr = e & 3;
            int row = m0 + wm + mt * 16 + quad * 4 + rr;
            atomicAdd(&rs[z * BC + row], v);
        }
    }
}

// ---------------------------------------------------------------------------
// GEMM2 merged (R8 measured-best 2-phase structure) + IN-BLOCK GATES:
// each block recomputes its batch's 4 gates from rs (wave si handles scale
// si; shuffle tree replicates gate_kernel's reduction order exactly:
// c+(c+64), then off=32..1). Removes the gate_kernel dispatch + gap.
// Grid (64,8) x=m fast: panel-sharing blocks id-congruent mod 8 -> same XCD.
// ---------------------------------------------------------------------------
__global__ __launch_bounds__(256, 2) void gemm2_kernel(
    const ushort_t* __restrict__ Hbase,   // H8 | H4 | H2, each [up|trend] 2*TOT
    const ushort_t* __restrict__ W2base,  // w2b8 | w2b4 | w2b2 contiguous
    const float* __restrict__ b2_8, const float* __restrict__ b2_4,
    const float* __restrict__ b2_2,
    const float* __restrict__ rs,
    const float* __restrict__ gw8, const float* __restrict__ gb8,
    const float* __restrict__ gw4, const float* __restrict__ gb4,
    const float* __restrict__ gw2, const float* __restrict__ gb2,
    const float* __restrict__ gw1, const float* __restrict__ gb1,
    const ushort_t* __restrict__ t1_bf, const ushort_t* __restrict__ xn_bf,
    float* __restrict__ trend_out, float* __restrict__ season_out)
{
    __shared__ ushort_t Asu[128 * 64];
    __shared__ ushort_t Ast[128 * 64];
    __shared__ ushort_t Bs[128 * 64];
    __shared__ float sgate[4];
    int tid  = threadIdx.x;
    int wave = tid >> 6;
    int lane = tid & 63;
    int m0 = blockIdx.x * 128, n0 = blockIdx.y * 128;   // M = 8192 rows
    int wm = (wave & 1) * 64, wn = (wave >> 1) * 64;
    int lrow = lane >> 3;
    int pc   = lane & 7;
    int fr   = lane & 15;
    int quad = lane >> 4;
    int b = m0 >> 7;                       // 128 rows = one batch

    // ---- in-block gate computation (replicates gate_kernel bit-for-bit) ----
    {
        const float* gw = (wave == 0) ? gw8 : (wave == 1) ? gw4
                        : (wave == 2) ? gw2 : gw1;
        const float* gb = (wave == 0) ? gb8 : (wave == 1) ? gb4
                        : (wave == 2) ? gb2 : gb1;
        const float* rsw = rs + (size_t)wave * BC + b * Cdim;
        // buf[c] = rs*(1/L)*gw[c]; first tree step: buf[c] += buf[c+64]
        float p = rsw[lane] * (1.f / Ldim) * gw[lane]
                + rsw[64 + lane] * (1.f / Ldim) * gw[64 + lane];
        // remaining tree steps off = 32..1 (same order as gate_kernel)
#pragma unroll
        for (int off = 32; off >= 1; off >>= 1)
            p += __shfl_down(p, off);
        if (lane == 0) {
            float zv = p + gb[0];
            sgate[wave] = 1.f / (1.f + expf(-zv));
        }
    }
    __syncthreads();
    float gsum = sgate[0] + sgate[1] + sgate[2] + sgate[3] + 1e-6f;
    float gv0 = sgate[0] / gsum, gv1 = sgate[1] / gsum;
    float gv2 = sgate[2] / gsum, g1  = sgate[3] / gsum;
    float gsv[3] = {gv0, gv1, gv2};

    f32x4 accu[4][4], acct[4][4];
#pragma unroll
    for (int i = 0; i < 4; ++i)
#pragma unroll
        for (int j = 0; j < 4; ++j) {
            accu[i][j] = (f32x4){0.f, 0.f, 0.f, 0.f};
            acct[i][j] = (f32x4){0.f, 0.f, 0.f, 0.f};
        }

    for (int s = 0; s < 3; ++s) {
        if (s > 0) {
            float rr_ = gsv[s - 1] / fmaxf(gsv[s], 1e-30f);
#pragma unroll
            for (int mt = 0; mt < 4; ++mt)
#pragma unroll
                for (int nt = 0; nt < 4; ++nt)
#pragma unroll
                    for (int rr = 0; rr < 4; ++rr) {
                        accu[mt][nt][rr] *= rr_;
                        acct[mt][nt][rr] *= rr_;
                    }
        }
        const ushort_t* Au = Hbase + (size_t)s * 2 * TOT;       // up half
        const ushort_t* At = Au + TOT;                          // trend half
        const ushort_t* Bw = W2base + (size_t)s * 1048576;
        for (int k0 = 0; k0 < 1024; k0 += 64) {
            __syncthreads();
#pragma unroll
            for (int i = 0; i < 4; ++i) {
                int rb  = wave * 32 + i * 8;
                int row = rb + lrow;
                int lc  = (pc - row) & 7;
                size_t goff = (size_t)(m0 + row) * 1024 + k0 + lc * 8;
                async16(Au + goff, &Asu[rb * 64]);
                async16(At + goff, &Ast[rb * 64]);
                async16(Bw + (size_t)(n0 + row) * 1024 + k0 + lc * 8, &Bs[rb * 64]);
            }
            __syncthreads();
#pragma unroll
            for (int kk = 0; kk < 64; kk += 32) {
                s16x8 af[4], bfr[4];
                int lcA = (kk >> 3) + quad;
#pragma unroll
                for (int t = 0; t < 4; ++t) {
                    int nr  = wn + t * 16 + fr;
                    bfr[t] = *(const s16x8*)&Bs[nr * 64 + ((lcA + nr) & 7) * 8];
                }
#pragma unroll
                for (int t = 0; t < 4; ++t) {
                    int mr  = wm + t * 16 + fr;
                    af[t]  = *(const s16x8*)&Asu[mr * 64 + ((lcA + mr) & 7) * 8];
                }
#pragma unroll
                for (int mt = 0; mt < 4; ++mt)
#pragma unroll
                    for (int nt = 0; nt < 4; ++nt)
                        accu[mt][nt] = __builtin_amdgcn_mfma_f32_16x16x32_bf16(
                            af[mt], bfr[nt], accu[mt][nt], 0, 0, 0);
#pragma unroll
                for (int t = 0; t < 4; ++t) {
                    int mr  = wm + t * 16 + fr;
                    af[t]  = *(const s16x8*)&Ast[mr * 64 + ((lcA + mr) & 7) * 8];
                }
#pragma unroll
                for (int mt = 0; mt < 4; ++mt)
#pragma unroll
                    for (int nt = 0; nt < 4; ++nt)
                        acct[mt][nt] = __builtin_amdgcn_mfma_f32_16x16x32_bf16(
                            af[mt], bfr[nt], acct[mt][nt], 0, 0, 0);
            }
        }
    }
#pragma unroll
    for (int mt = 0; mt < 4; ++mt)
#pragma unroll
        for (int nt = 0; nt < 4; ++nt)
#pragma unroll
            for (int rr = 0; rr < 4; ++rr) {
                accu[mt][nt][rr] *= gv2;
                acct[mt][nt][rr] *= gv2;
            }

    // epilogue — D layout: m = quad*4 + reg, n = lane&15; trend in-register
#pragma unroll
    for (int mt = 0; mt < 4; ++mt)
#pragma unroll
        for (int nt = 0; nt < 4; ++nt) {
            int col = n0 + wn + nt * 16 + fr;
            float cb2 = gv0 * b2_8[col] + gv1 * b2_4[col] + gv2 * b2_2[col];
#pragma unroll
            for (int r = 0; r < 4; ++r) {
                size_t row = m0 + wm + mt * 16 + quad * 4 + r;
                size_t idx = row * 1024 + col;
                float tr = acct[mt][nt][r] + cb2 + g1 * bf2f(t1_bf[idx]);
                float se = accu[mt][nt][r] + cb2 + g1 * bf2f(xn_bf[idx]) - tr;
                trend_out[idx]  = tr;
                season_out[idx] = se;
            }
        }
}

// ---------------------------------------------------------------------------
extern "C" void kernel_launch(void* const* d_in, const int* in_sizes, int n_in,
                              void* d_out, int out_size, void* d_ws, size_t ws_size,
                              hipStream_t stream)
{
    const float* x    = (const float*)d_in[0];
    const float* bn_g = (const float*)d_in[1];
    const float* bn_b = (const float*)d_in[2];
    const float* cw8  = (const float*)d_in[3];
    const float* w1_8 = (const float*)d_in[4];
    const float* b1_8 = (const float*)d_in[5];
    const float* w2_8 = (const float*)d_in[6];
    const float* b2_8 = (const float*)d_in[7];
    const float* cw4  = (const float*)d_in[8];
    const float* w1_4 = (const float*)d_in[9];
    const float* b1_4 = (const float*)d_in[10];
    const float* w2_4 = (const float*)d_in[11];
    const float* b2_4 = (const float*)d_in[12];
    const float* cw2  = (const float*)d_in[13];
    const float* w1_2 = (const float*)d_in[14];
    const float* b1_2 = (const float*)d_in[15];
    const float* w2_2 = (const float*)d_in[16];
    const float* b2_2 = (const float*)d_in[17];
    const float* gw8  = (const float*)d_in[18];
    const float* gb8  = (const float*)d_in[19];
    const float* al8  = (const float*)d_in[20];
    const float* gw4  = (const float*)d_in[21];
    const float* gb4  = (const float*)d_in[22];
    const float* al4  = (const float*)d_in[23];
    const float* gw2  = (const float*)d_in[24];
    const float* gb2  = (const float*)d_in[25];
    const float* al2  = (const float*)d_in[26];
    const float* gw1  = (const float*)d_in[27];
    const float* gb1  = (const float*)d_in[28];
    const float* al1  = (const float*)d_in[29];

    // workspace (~140 MB)
    ushort_t* p_xn  = (ushort_t*)d_ws;                 // TOT bf16
    ushort_t* p_t1  = p_xn + TOT;                      // TOT bf16
    ushort_t* p_H   = p_t1 + TOT;                      // 6*TOT bf16 (H8|H4|H2)
    ushort_t* p_wb  = p_H + 6 * (size_t)TOT;           // 4063232 bf16 weights
    ushort_t* p_w1b = p_wb;                            // w1b8|w1b4|w1b2
    ushort_t* p_w2b = p_wb + 917504;                   // w2b8|w2b4|w2b2
    float*    p_sc  = (float*)(p_wb + 4063232);        // CLn
    float*    p_sh  = p_sc + CLn;                      // CLn
    float*    p_w2cs = p_sh + CLn;                     // 3*1024
    float*    p_rs  = p_w2cs + 3 * 1024;               // 4*BC
    // EMA coef tables alias the (not-yet-written) H buffer (stream-ordered).
    float*    p_coef = (float*)p_H;                    // 128*1920 floats
    float*    p_am   = p_coef + 128 * 1920;            // 128*8 floats
    // A-tiles (bf16 down|trend per scale) aliased into d_out season half
    ushort_t* p_A8 = (ushort_t*)d_out;                 // 2*BC*128
    ushort_t* p_A4 = p_A8 + 2 * (size_t)BC * 128;      // 2*BC*256
    ushort_t* p_A2 = p_A4 + 2 * (size_t)BC * 256;      // 2*BC*512
    float*    p_season = (float*)d_out;
    float*    p_trend  = (float*)d_out + TOT;

    // ONE fused prep launch: weights->bf16, BN stats, W2 colsums, EMA coef,
    // rs zero.
    prep_kernel<<<PREP_TOTAL, 256, 0, stream>>>(
        w1_8, w1_4, w1_2, w2_8, w2_4, w2_2, p_wb,
        x, bn_g, bn_b, p_sc, p_sh,
        p_w2cs,
        al1, al2, al4, al8, p_coef, p_am,
        p_rs);

    // fused xn + conv x3 + EMA x4 + scale-1 rowdiff
    pre_kernel<<<BC, 256, 0, stream>>>(x, p_sc, p_sh, cw8, cw4, cw2,
                                       p_coef, p_am,
                                       p_xn, p_t1, p_A8, p_A4, p_A2, p_rs);

    // merged GEMM1 (up+trend halves, shared W1 tile, fused gate row-sums)
    gemm1_kernel<<<dim3(192, 8), 256, 0, stream>>>(
        p_A8, p_w1b, b1_8, b1_4, b1_2, p_w2cs, p_H, p_rs);

    // merged GEMM2 with in-block gates: trend + season in one pass
    gemm2_kernel<<<dim3(64, 8), 256, 0, stream>>>(
        p_H, p_w2b, b2_8, b2_4, b2_2,
        p_rs, gw8, gb8, gw4, gb4, gw2, gb2, gw1, gb1,
        p_t1, p_xn, p_trend, p_season);
}